// Round 12
// baseline (129.142 us; speedup 1.0000x reference)
//
#include <hip/hip_runtime.h>
#include <hip/hip_bf16.h>

#define S_LEN 2048
#define NHEAD 16
#define HDIM 64
#define HID 1024
#define BATCH 2
#define TSTR 136   // T-buffer stride (shorts)

typedef __attribute__((ext_vector_type(8))) short s16x8;
typedef __attribute__((ext_vector_type(4))) short s16x4;
typedef __attribute__((ext_vector_type(4))) float f32x4;

__device__ __forceinline__ short f2bf(float f) {
    union { __hip_bfloat16 b; short s; } u;
    u.b = __float2bfloat16(f);
    return u.s;
}
__device__ __forceinline__ float fexp2(float x) {
    return __builtin_amdgcn_exp2f(x);
}
__device__ __forceinline__ f32x4 mfma16(s16x8 a, s16x8 b, f32x4 c) {
    return __builtin_amdgcn_mfma_f32_16x16x32_bf16(a, b, c, 0, 0, 0);
}
__device__ __forceinline__ void gload16(const short* g, short* l) {
    __builtin_amdgcn_global_load_lds(
        (const __attribute__((address_space(1))) void*)g,
        (__attribute__((address_space(3))) void*)l, 16, 0, 0);
}
// pack two f32 -> one u32 of 2 bf16 (round-half-up, inputs finite >=0)
__device__ __forceinline__ unsigned bfpack(float a, float b) {
    unsigned ua = __builtin_bit_cast(unsigned, a) + 0x8000u;
    unsigned ub = __builtin_bit_cast(unsigned, b) + 0x8000u;
    return (ub & 0xFFFF0000u) | (ua >> 16);
}

// ---------------------------------------------------------------------------
// Kernel 0: one-shot fp32 -> bf16 conversion of x and all weights.
// ---------------------------------------------------------------------------
__global__ __launch_bounds__(256) void convert_kernel(
    const float* __restrict__ x,  const float* __restrict__ wq,
    const float* __restrict__ wk, const float* __restrict__ wv,
    const float* __restrict__ wo,
    short* __restrict__ xb, short* __restrict__ wcat, short* __restrict__ wob)
{
    const int F4X = 1048576, F4W = 262144;
    const int total = F4X + 4 * F4W;
    for (int i = blockIdx.x * blockDim.x + threadIdx.x; i < total;
         i += gridDim.x * blockDim.x) {
        const float4* s; short* d; int off;
        if (i < F4X)              { s = (const float4*)x;  d = xb;             off = i; }
        else if (i < F4X + F4W)   { s = (const float4*)wq; d = wcat;           off = i - F4X; }
        else if (i < F4X + 2*F4W) { s = (const float4*)wk; d = wcat + 1048576; off = i - (F4X + F4W); }
        else if (i < F4X + 3*F4W) { s = (const float4*)wv; d = wcat + 2097152; off = i - (F4X + 2*F4W); }
        else                      { s = (const float4*)wo; d = wob;            off = i - (F4X + 3*F4W); }
        float4 v = s[off];
        s16x4 o4 = { f2bf(v.x), f2bf(v.y), f2bf(v.z), f2bf(v.w) };
        *(s16x4*)(d + (size_t)off * 4) = o4;
    }
}

// ---------------------------------------------------------------------------
// Kernel 1: fused QKV GEMM (unchanged from R11: Q pre-scaled 0.125, K by
// log2e, so attention exp2's raw MFMA output directly).
// ---------------------------------------------------------------------------
__global__ __launch_bounds__(256) void qkv_gemm2(
    const short* __restrict__ xb, const short* __restrict__ wcat,
    short* __restrict__ q_ws, short* __restrict__ k_ws, short* __restrict__ vt_ws)
{
    __shared__ union SM {
        struct { short A[128][64]; short B[128][64]; } s;
        short T[128][TSTR];
    } sm;
    const int t = threadIdx.x;
    const int lane = t & 63, w = t >> 6;
    const int g = lane >> 4, r15 = lane & 15;
    const int wm = w >> 1, wn = w & 1;
    const int bid = blockIdx.x;
    const int cx = bid & 7, ii = bid >> 3;
    const int mt = cx * 4 + (ii & 3), nt = ii >> 2;
    const int m0 = mt * 128, n0 = nt * 128;
    const int sel = n0 >> 10;
    const int nr0 = n0 & 1023;
    const short* Ag = (sel == 2) ? (wcat + (size_t)(2048 + nr0) * 1024)
                                 : (xb   + (size_t)m0 * 1024);
    const short* Bg = (sel == 2) ? (xb   + (size_t)m0 * 1024)
                                 : (wcat + (size_t)(sel * 1024 + nr0) * 1024);
    const int lrow = lane >> 3;
    const int scol = ((lane & 7) ^ lrow) * 8;
    const int rsw = r15 & 7;
    const float osc = (sel == 0) ? 0.125f : ((sel == 1) ? 1.44269504f : 1.0f);

    f32x4 acc[4][4] = {};

    for (int k0 = 0; k0 < 1024; k0 += 64) {
        __syncthreads();
        #pragma unroll
        for (int ch = 0; ch < 4; ++ch) {
            const int row = w * 32 + ch * 8;
            gload16(Ag + (size_t)(row + lrow) * 1024 + k0 + scol, &sm.s.A[row][0]);
            gload16(Bg + (size_t)(row + lrow) * 1024 + k0 + scol, &sm.s.B[row][0]);
        }
        __syncthreads();
        #pragma unroll
        for (int kk = 0; kk < 2; ++kk) {
            s16x8 af[4], bfr[4];
            #pragma unroll
            for (int mi = 0; mi < 4; ++mi)
                af[mi] = *(const s16x8*)&sm.s.A[wm * 64 + mi * 16 + r15][((kk * 4 + g) ^ rsw) * 8];
            #pragma unroll
            for (int ni = 0; ni < 4; ++ni)
                bfr[ni] = *(const s16x8*)&sm.s.B[wn * 64 + ni * 16 + r15][((kk * 4 + g) ^ rsw) * 8];
            #pragma unroll
            for (int mi = 0; mi < 4; ++mi)
                #pragma unroll
                for (int ni = 0; ni < 4; ++ni)
                    acc[mi][ni] = mfma16(af[mi], bfr[ni], acc[mi][ni]);
        }
    }

    __syncthreads();
    #pragma unroll
    for (int mi = 0; mi < 4; ++mi)
    #pragma unroll
    for (int ni = 0; ni < 4; ++ni)
        #pragma unroll
        for (int reg = 0; reg < 4; ++reg)
            sm.T[wm * 64 + mi * 16 + g * 4 + reg][wn * 64 + ni * 16 + r15]
                = f2bf(acc[mi][ni][reg] * osc);
    __syncthreads();

    const int b = m0 >> 11;
    const int ms = m0 & 2047;
    #pragma unroll
    for (int it = 0; it < 8; ++it) {
        int u = w + it * 4;
        int half = u & 1;
        int rg = u >> 1;
        int r = rg * 8 + lrow;
        int colc = half * 64 + (lane & 7) * 8;
        s16x8 v = *(const s16x8*)&sm.T[r][colc];
        if (sel == 2) {
            int n = nr0 + r;
            int h = n >> 6, d = n & 63;
            *(s16x8*)(vt_ws + ((size_t)(b * NHEAD + h) * HDIM + d) * S_LEN + ms + colc) = v;
        } else {
            int s = ms + r;
            int n = nr0 + colc;
            int h = n >> 6, d = n & 63;
            short* dst = (sel == 0) ? q_ws : k_ws;
            *(s16x8*)(dst + ((size_t)(b * NHEAD + h) * S_LEN + s) * HDIM + d) = v;
        }
    }
}

// ---------------------------------------------------------------------------
// Kernel 2: causal flash attention, SPLIT-K WAVE PAIRS + Mq=32.
// 512 blocks x 256 thr (4 waves).  Block = uniform pair (pi, 31-pi) of
// 64-row q-tiles (33 KV-tiles total, every block).  Waves {0,1} handle keys
// [0,32), waves {2,3} keys [32,64) of every KV tile; each wave owns 32
// q-rows (2 m-subtiles).  All share one dbuf KV LDS stream -> per-CU LDS
// traffic HALVES vs R11.  Max-free softmax (R11) makes the split-K combine
// exact: o_A+o_B, l_A+l_B via an LDS scratch at each phase end.
// ---------------------------------------------------------------------------
__global__ __launch_bounds__(256) void attn_kernel7(
    const short* __restrict__ q_ws, const short* __restrict__ k_ws,
    const short* __restrict__ vt_ws, short* __restrict__ attn_ws)
{
    __shared__ union SMEM {
        struct { short Ks[2][64][64]; short Vts[2][64][64]; } kv;   // 32 KB
        struct { float obuf[64][68]; float lbuf[64][4]; } cb;       // 18.4 KB
    } sm;
    const int t = threadIdx.x;
    const int lane = t & 63, w = t >> 6;          // w 0..3
    const int g = lane >> 4, r15 = lane & 15;
    const int kh = w >> 1;                        // key half: 0 or 1
    const int qsub = w & 1;                       // q half of the 64-row tile
    const int khof = kh * 32;
    const int bid = blockIdx.x;
    const int lb = (bid & 7) * 64 + (bid >> 3);   // XCD-chunked, 512%8==0
    const int pi = lb & 15;                       // pair index 0..15
    const int bh = lb >> 4;                       // 0..31
    const size_t base = (size_t)bh * S_LEN * HDIM;
    const int swr = (r15 & 7) << 3;
    const int b = bh >> 4, h = bh & 15;

    // staging geometry: 256 thr cover 32 rows x 8 chunks per pass; 2 passes
    const int r0 = t >> 3, c0 = (t & 7) * 8;      // r0 0..31
    const int cx0 = c0 ^ ((r0 & 7) << 3);         // (r0&7) invariant under +32

    union P8 { unsigned u[4]; s16x8 v; };
    union V8 { s16x4 h[2]; s16x8 v; };

    for (int phase = 0; phase < 2; ++phase) {
        const int qt = phase ? (31 - pi) : pi;    // 64-row tile index 0..31
        const int q0 = qt * 64;
        const int ntk = qt + 1;

        // Q fragments: rows q0 + qsub*32 + m*16 + r15
        s16x8 qf[2][2];
        #pragma unroll
        for (int m = 0; m < 2; ++m)
            #pragma unroll
            for (int c = 0; c < 2; ++c)
                qf[m][c] = *(const s16x8*)(q_ws + base +
                    (size_t)(q0 + qsub * 32 + m * 16 + r15) * HDIM + c * 32 + g * 8);
        f32x4 o[2][4] = {};
        float lr[2] = { 0.f, 0.f };

        // prologue: stage KV tile 0 into buffer 0 (2 passes of 32 rows)
        #pragma unroll
        for (int j = 0; j < 2; ++j) {
            int r = r0 + j * 32;
            *(s16x8*)&sm.kv.Ks[0][r][cx0]  = *(const s16x8*)(k_ws  + base + (size_t)r * HDIM + c0);
            *(s16x8*)&sm.kv.Vts[0][r][cx0] = *(const s16x8*)(vt_ws + base + (size_t)r * S_LEN + c0);
        }
        __syncthreads();

        const short* kp = k_ws  + base + (size_t)(64 + r0) * HDIM + c0;
        const short* vp = vt_ws + base + (size_t)r0 * S_LEN + 64 + c0;

        for (int kt = 0; kt < ntk; ++kt) {
            const int cur = kt & 1;
            const bool pre = (kt + 1 < ntk);
            const bool dg = (kt == ntk - 1);
            s16x8 ka[2], va[2];
            if (pre) {
                ka[0] = *(const s16x8*)kp;
                ka[1] = *(const s16x8*)(kp + (size_t)32 * HDIM);
                va[0] = *(const s16x8*)vp;
                va[1] = *(const s16x8*)(vp + (size_t)32 * S_LEN);
                kp += (size_t)64 * HDIM; vp += 64;
            }

            // ---- LDS fragment reads: this wave's key half only ----
            s16x8 kfa[2][2];
            #pragma unroll
            for (int f = 0; f < 2; ++f)
                #pragma unroll
                for (int c = 0; c < 2; ++c)
                    kfa[f][c] = *(const s16x8*)&sm.kv.Ks[cur][khof + f * 16 + r15][(c * 32 + g * 8) ^ swr];
            V8 vfr[4];
            #pragma unroll
            for (int f2 = 0; f2 < 4; ++f2) {
                vfr[f2].h[0] = *(const s16x4*)&sm.kv.Vts[cur][f2 * 16 + r15][(khof + g * 4) ^ swr];
                vfr[f2].h[1] = *(const s16x4*)&sm.kv.Vts[cur][f2 * 16 + r15][(khof + 16 + g * 4) ^ swr];
            }

            // ---- QK^T (both m-subtiles) ----
            f32x4 z[2][2];
            __builtin_amdgcn_s_setprio(1);
            #pragma unroll
            for (int m = 0; m < 2; ++m)
                #pragma unroll
                for (int f = 0; f < 2; ++f) {
                    f32x4 zz = { 0.f, 0.f, 0.f, 0.f };
                    zz = mfma16(kfa[f][0], qf[m][0], zz);
                    zz = mfma16(kfa[f][1], qf[m][1], zz);
                    z[m][f] = zz;
                }
            __builtin_amdgcn_s_setprio(0);

            // ---- causal mask (diagonal tile: kv0 == q0, so qrel is local) ----
            if (dg) {
                #pragma unroll
                for (int m = 0; m < 2; ++m) {
                    const int qrel = qsub * 32 + m * 16 + r15;
                    #pragma unroll
                    for (int f = 0; f < 2; ++f)
                        #pragma unroll
                        for (int reg = 0; reg < 4; ++reg)
                            if (khof + f * 16 + g * 4 + reg > qrel) z[m][f][reg] = -3e30f;
                }
            }

            // ---- direct exp2 + pack + per-lane sum ----
            P8 p8[2];
            #pragma unroll
            for (int m = 0; m < 2; ++m)
                #pragma unroll
                for (int f = 0; f < 2; ++f) {
                    float e0 = fexp2(z[m][f][0]);
                    float e1 = fexp2(z[m][f][1]);
                    float e2 = fexp2(z[m][f][2]);
                    float e3 = fexp2(z[m][f][3]);
                    lr[m] += (e0 + e1) + (e2 + e3);
                    p8[m].u[2 * f]     = bfpack(e0, e1);
                    p8[m].u[2 * f + 1] = bfpack(e2, e3);
                }

            // ---- PV at K=32 (consistent k-permutation across A and B) ----
            __builtin_amdgcn_s_setprio(1);
            #pragma unroll
            for (int m = 0; m < 2; ++m)
                #pragma unroll
                for (int f2 = 0; f2 < 4; ++f2)
                    o[m][f2] = mfma16(vfr[f2].v, p8[m].v, o[m][f2]);
            __builtin_amdgcn_s_setprio(0);

            if (pre) {
                #pragma unroll
                for (int j = 0; j < 2; ++j) {
                    int r = r0 + j * 32;
                    *(s16x8*)&sm.kv.Ks[cur ^ 1][r][cx0]  = ka[j];
                    *(s16x8*)&sm.kv.Vts[cur ^ 1][r][cx0] = va[j];
                }
            }
            __syncthreads();
        }

        // ---- split-K combine: (o,l) = A-half + B-half, exact (max-free) ----
        if (kh == 1) {
            #pragma unroll
            for (int m = 0; m < 2; ++m) {
                #pragma unroll
                for (int f2 = 0; f2 < 4; ++f2)
                    *(f32x4*)&sm.cb.obuf[qsub * 32 + m * 16 + r15][f2 * 16 + g * 4] = o[m][f2];
                sm.cb.lbuf[qsub * 32 + m * 16 + r15][g] = lr[m];
            }
        }
        __syncthreads();
        if (kh == 0) {
            #pragma unroll
            for (int m = 0; m < 2; ++m) {
                #pragma unroll
                for (int f2 = 0; f2 < 4; ++f2)
                    o[m][f2] += *(const f32x4*)&sm.cb.obuf[qsub * 32 + m * 16 + r15][f2 * 16 + g * 4];
                lr[m] += sm.cb.lbuf[qsub * 32 + m * 16 + r15][g];
                float l = lr[m];
                l += __shfl_xor(l, 16);
                l += __shfl_xor(l, 32);
                float inv = 1.f / (l + 1e-8f);
                const int qg = q0 + qsub * 32 + m * 16 + r15;
                size_t obase = ((size_t)b * S_LEN + qg) * HID + h * HDIM + g * 4;
                #pragma unroll
                for (int f2 = 0; f2 < 4; ++f2) {
                    s16x4 ov = { f2bf(o[m][f2][0] * inv), f2bf(o[m][f2][1] * inv),
                                 f2bf(o[m][f2][2] * inv), f2bf(o[m][f2][3] * inv) };
                    *(s16x4*)(attn_ws + obase + f2 * 16) = ov;
                }
            }
        }
        __syncthreads();   // scratch + buffers free before next phase restage
    }
}

// ---------------------------------------------------------------------------
// Kernel 3: out = attn(bf16) @ wob.T -> fp32 (unchanged).
// ---------------------------------------------------------------------------
__global__ __launch_bounds__(256) void wo_gemm2(
    const short* __restrict__ attn, const short* __restrict__ wob,
    float* __restrict__ out)
{
    __shared__ short As[128][64];
    __shared__ short Bs[128][64];
    const int t = threadIdx.x;
    const int lane = t & 63, w = t >> 6;
    const int g = lane >> 4, r15 = lane & 15;
    const int wm = w >> 1, wn = w & 1;
    const int bid = blockIdx.x;
    const int cx = bid & 7, ii = bid >> 3;
    const int mt = cx * 4 + (ii & 3), nt = ii >> 2;
    const int m0 = mt * 128, n0 = nt * 128;
    const int lrow = lane >> 3;
    const int scol = ((lane & 7) ^ lrow) * 8;
    const int rsw = r15 & 7;

    f32x4 acc[4][4] = {};

    for (int k0 = 0; k0 < 1024; k0 += 64) {
        __syncthreads();
        #pragma unroll
        for (int ch = 0; ch < 4; ++ch) {
            const int row = w * 32 + ch * 8;
            gload16(attn + (size_t)(m0 + row + lrow) * 1024 + k0 + scol, &As[row][0]);
            gload16(wob  + (size_t)(n0 + row + lrow) * 1024 + k0 + scol, &Bs[row][0]);
        }
        __syncthreads();
        #pragma unroll
        for (int kk = 0; kk < 2; ++kk) {
            s16x8 af[4], bfr[4];
            #pragma unroll
            for (int mi = 0; mi < 4; ++mi)
                af[mi] = *(const s16x8*)&As[wm * 64 + mi * 16 + r15][((kk * 4 + g) ^ rsw) * 8];
            #pragma unroll
            for (int ni = 0; ni < 4; ++ni)
                bfr[ni] = *(const s16x8*)&Bs[wn * 64 + ni * 16 + r15][((kk * 4 + g) ^ rsw) * 8];
            #pragma unroll
            for (int mi = 0; mi < 4; ++mi)
                #pragma unroll
                for (int ni = 0; ni < 4; ++ni)
                    acc[mi][ni] = mfma16(af[mi], bfr[ni], acc[mi][ni]);
        }
    }

    #pragma unroll
    for (int mi = 0; mi < 4; ++mi)
    #pragma unroll
    for (int ni = 0; ni < 4; ++ni) {
        #pragma unroll
        for (int reg = 0; reg < 4; ++reg) {
            int m = m0 + wm * 64 + mi * 16 + g * 4 + reg;
            int n = n0 + wn * 64 + ni * 16 + r15;
            out[(size_t)m * 1024 + n] = acc[mi][ni][reg];
        }
    }
}

extern "C" void kernel_launch(void* const* d_in, const int* in_sizes, int n_in,
                              void* d_out, int out_size, void* d_ws, size_t ws_size,
                              hipStream_t stream) {
    const float* x  = (const float*)d_in[0];
    const float* wq = (const float*)d_in[1];
    const float* wk = (const float*)d_in[2];
    const float* wv = (const float*)d_in[3];
    const float* wo = (const float*)d_in[4];
    float* out = (float*)d_out;

    const size_t ELEMS = (size_t)BATCH * S_LEN * HID;   // 4,194,304
    short* q_ws    = (short*)d_ws;
    short* k_ws    = q_ws + ELEMS;
    short* vt_ws   = k_ws + ELEMS;
    short* xb      = vt_ws + ELEMS;        // aliased: xb (k0/k1) then attn (k2/k3)
    short* attn_ws = xb;
    short* wcat    = xb + ELEMS;           // 3,145,728
    short* wob     = wcat + 3145728;       // 1,048,576   total ~42MB

    convert_kernel<<<dim3(2048), dim3(256), 0, stream>>>(x, wq, wk, wv, wo, xb, wcat, wob);
    qkv_gemm2<<<dim3(768), dim3(256), 0, stream>>>(xb, wcat, q_ws, k_ws, vt_ws);
    attn_kernel7<<<dim3(512), dim3(256), 0, stream>>>(q_ws, k_ws, vt_ws, attn_ws);
    wo_gemm2<<<dim3(256), dim3(256), 0, stream>>>(attn_ws, wob, out);
}

// Round 13
// 120.575 us; speedup vs baseline: 1.0710x; 1.0710x over previous
//
#include <hip/hip_runtime.h>
#include <hip/hip_bf16.h>

#define S_LEN 2048
#define NHEAD 16
#define HDIM 64
#define HID 1024
#define BATCH 2
#define TSTR 136   // T-buffer stride (shorts)

typedef __attribute__((ext_vector_type(8))) short s16x8;
typedef __attribute__((ext_vector_type(4))) short s16x4;
typedef __attribute__((ext_vector_type(4))) float f32x4;

__device__ __forceinline__ short f2bf(float f) {
    union { __hip_bfloat16 b; short s; } u;
    u.b = __float2bfloat16(f);
    return u.s;
}
__device__ __forceinline__ float fexp2(float x) {
    return __builtin_amdgcn_exp2f(x);
}
__device__ __forceinline__ f32x4 mfma16(s16x8 a, s16x8 b, f32x4 c) {
    return __builtin_amdgcn_mfma_f32_16x16x32_bf16(a, b, c, 0, 0, 0);
}
__device__ __forceinline__ void gload16(const short* g, short* l) {
    __builtin_amdgcn_global_load_lds(
        (const __attribute__((address_space(1))) void*)g,
        (__attribute__((address_space(3))) void*)l, 16, 0, 0);
}
// pack two f32 -> one u32 of 2 bf16 (round-half-up, inputs finite >=0)
__device__ __forceinline__ unsigned bfpack(float a, float b) {
    unsigned ua = __builtin_bit_cast(unsigned, a) + 0x8000u;
    unsigned ub = __builtin_bit_cast(unsigned, b) + 0x8000u;
    return (ub & 0xFFFF0000u) | (ua >> 16);
}

// ---------------------------------------------------------------------------
// Kernel 0: one-shot fp32 -> bf16 conversion of x and all weights.
// ---------------------------------------------------------------------------
__global__ __launch_bounds__(256) void convert_kernel(
    const float* __restrict__ x,  const float* __restrict__ wq,
    const float* __restrict__ wk, const float* __restrict__ wv,
    const float* __restrict__ wo,
    short* __restrict__ xb, short* __restrict__ wcat, short* __restrict__ wob)
{
    const int F4X = 1048576, F4W = 262144;
    const int total = F4X + 4 * F4W;
    for (int i = blockIdx.x * blockDim.x + threadIdx.x; i < total;
         i += gridDim.x * blockDim.x) {
        const float4* s; short* d; int off;
        if (i < F4X)              { s = (const float4*)x;  d = xb;             off = i; }
        else if (i < F4X + F4W)   { s = (const float4*)wq; d = wcat;           off = i - F4X; }
        else if (i < F4X + 2*F4W) { s = (const float4*)wk; d = wcat + 1048576; off = i - (F4X + F4W); }
        else if (i < F4X + 3*F4W) { s = (const float4*)wv; d = wcat + 2097152; off = i - (F4X + 2*F4W); }
        else                      { s = (const float4*)wo; d = wob;            off = i - (F4X + 3*F4W); }
        float4 v = s[off];
        s16x4 o4 = { f2bf(v.x), f2bf(v.y), f2bf(v.z), f2bf(v.w) };
        *(s16x4*)(d + (size_t)off * 4) = o4;
    }
}

// ---------------------------------------------------------------------------
// Kernel 1: fused QKV GEMM (unchanged: Q pre-scaled 0.125, K by log2e).
// ---------------------------------------------------------------------------
__global__ __launch_bounds__(256) void qkv_gemm2(
    const short* __restrict__ xb, const short* __restrict__ wcat,
    short* __restrict__ q_ws, short* __restrict__ k_ws, short* __restrict__ vt_ws)
{
    __shared__ union SM {
        struct { short A[128][64]; short B[128][64]; } s;
        short T[128][TSTR];
    } sm;
    const int t = threadIdx.x;
    const int lane = t & 63, w = t >> 6;
    const int g = lane >> 4, r15 = lane & 15;
    const int wm = w >> 1, wn = w & 1;
    const int bid = blockIdx.x;
    const int cx = bid & 7, ii = bid >> 3;
    const int mt = cx * 4 + (ii & 3), nt = ii >> 2;
    const int m0 = mt * 128, n0 = nt * 128;
    const int sel = n0 >> 10;
    const int nr0 = n0 & 1023;
    const short* Ag = (sel == 2) ? (wcat + (size_t)(2048 + nr0) * 1024)
                                 : (xb   + (size_t)m0 * 1024);
    const short* Bg = (sel == 2) ? (xb   + (size_t)m0 * 1024)
                                 : (wcat + (size_t)(sel * 1024 + nr0) * 1024);
    const int lrow = lane >> 3;
    const int scol = ((lane & 7) ^ lrow) * 8;
    const int rsw = r15 & 7;
    const float osc = (sel == 0) ? 0.125f : ((sel == 1) ? 1.44269504f : 1.0f);

    f32x4 acc[4][4] = {};

    for (int k0 = 0; k0 < 1024; k0 += 64) {
        __syncthreads();
        #pragma unroll
        for (int ch = 0; ch < 4; ++ch) {
            const int row = w * 32 + ch * 8;
            gload16(Ag + (size_t)(row + lrow) * 1024 + k0 + scol, &sm.s.A[row][0]);
            gload16(Bg + (size_t)(row + lrow) * 1024 + k0 + scol, &sm.s.B[row][0]);
        }
        __syncthreads();
        #pragma unroll
        for (int kk = 0; kk < 2; ++kk) {
            s16x8 af[4], bfr[4];
            #pragma unroll
            for (int mi = 0; mi < 4; ++mi)
                af[mi] = *(const s16x8*)&sm.s.A[wm * 64 + mi * 16 + r15][((kk * 4 + g) ^ rsw) * 8];
            #pragma unroll
            for (int ni = 0; ni < 4; ++ni)
                bfr[ni] = *(const s16x8*)&sm.s.B[wn * 64 + ni * 16 + r15][((kk * 4 + g) ^ rsw) * 8];
            #pragma unroll
            for (int mi = 0; mi < 4; ++mi)
                #pragma unroll
                for (int ni = 0; ni < 4; ++ni)
                    acc[mi][ni] = mfma16(af[mi], bfr[ni], acc[mi][ni]);
        }
    }

    __syncthreads();
    #pragma unroll
    for (int mi = 0; mi < 4; ++mi)
    #pragma unroll
    for (int ni = 0; ni < 4; ++ni)
        #pragma unroll
        for (int reg = 0; reg < 4; ++reg)
            sm.T[wm * 64 + mi * 16 + g * 4 + reg][wn * 64 + ni * 16 + r15]
                = f2bf(acc[mi][ni][reg] * osc);
    __syncthreads();

    const int b = m0 >> 11;
    const int ms = m0 & 2047;
    #pragma unroll
    for (int it = 0; it < 8; ++it) {
        int u = w + it * 4;
        int half = u & 1;
        int rg = u >> 1;
        int r = rg * 8 + lrow;
        int colc = half * 64 + (lane & 7) * 8;
        s16x8 v = *(const s16x8*)&sm.T[r][colc];
        if (sel == 2) {
            int n = nr0 + r;
            int h = n >> 6, d = n & 63;
            *(s16x8*)(vt_ws + ((size_t)(b * NHEAD + h) * HDIM + d) * S_LEN + ms + colc) = v;
        } else {
            int s = ms + r;
            int n = nr0 + colc;
            int h = n >> 6, d = n & 63;
            short* dst = (sel == 0) ? q_ws : k_ws;
            *(s16x8*)(dst + ((size_t)(b * NHEAD + h) * S_LEN + s) * HDIM + d) = v;
        }
    }
}

// ---------------------------------------------------------------------------
// Kernel 2: causal flash attention, MERGED-PAIR KV STREAM.
// 1024 blocks x 128 thr (2 waves).  Block owns q-tiles A=pi and B=63-pi
// (32 rows each) but streams K/V ONCE over B's range: tile A computes on the
// shared fragments while kt < ntkA.  Staged+read tiles: 33 -> ntkB (avg 24.5,
// -26% LDS traffic); compute total unchanged; merged iters give 2 indep
// chains (ILP).  pi interleaved so any 4 co-resident blocks hold
// complementary pairs (CU-level balance, robust to dispatch order).
// All layouts/swizzles/inner math byte-identical to R11's proven kernel.
// ---------------------------------------------------------------------------
__global__ __launch_bounds__(128) void attn_kernel8(
    const short* __restrict__ q_ws, const short* __restrict__ k_ws,
    const short* __restrict__ vt_ws, short* __restrict__ attn_ws)
{
    __shared__ short Ks[2][64][64];
    __shared__ short Vts[2][64][64];
    const int t = threadIdx.x;
    const int lane = t & 63, w = t >> 6;          // w = 0,1
    const int g = lane >> 4, r15 = lane & 15;
    const int bid = blockIdx.x;
    const int cx = bid & 7, ii = bid >> 3;        // XCD-chunked, 1024%8==0
    const int bh = cx * 4 + (ii >> 5);            // 4 heads per XCD chunk
    const int v5 = ii & 31;
    const int pi = (v5 & 1) ? (31 - (v5 >> 1)) : (v5 >> 1);   // balanced interleave
    const size_t base = (size_t)bh * S_LEN * HDIM;
    const int swr = (r15 & 7) << 3;
    const int b = bh >> 4, h = bh & 15;

    const int r0 = t >> 3, c0 = (t & 7) * 8;      // r0 0..15
    const int cx0 = c0 ^ ((r0 & 7) << 3);

    union P8 { unsigned u[4]; s16x8 v; };
    union V8 { s16x4 h[2]; s16x8 v; };

    const int qtA = pi, qtB = 63 - pi;            // 32-row tile indices
    const int ntkA = (qtA >> 1) + 1;              // 1..16
    const int ntkB = (qtB >> 1) + 1;              // 17..32  (always > ntkA)
    const int qgA = qtA * 32 + w * 16 + r15;
    const int qgB = qtB * 32 + w * 16 + r15;
    const int qrelA = qgA - (ntkA - 1) * 64;      // 0..63 in A's diagonal tile
    const int qrelB = qgB - (ntkB - 1) * 64;

    s16x8 qfA0 = *(const s16x8*)(q_ws + base + (size_t)qgA * HDIM + g * 8);
    s16x8 qfA1 = *(const s16x8*)(q_ws + base + (size_t)qgA * HDIM + 32 + g * 8);
    s16x8 qfB0 = *(const s16x8*)(q_ws + base + (size_t)qgB * HDIM + g * 8);
    s16x8 qfB1 = *(const s16x8*)(q_ws + base + (size_t)qgB * HDIM + 32 + g * 8);
    f32x4 oA[4] = {}, oB[4] = {};
    float lrA = 0.f, lrB = 0.f;

    // prologue: stage KV tile 0 into buffer 0 (4 passes of 16 rows)
    #pragma unroll
    for (int j = 0; j < 4; ++j) {
        int r = r0 + j * 16;
        *(s16x8*)&Ks[0][r][cx0]  = *(const s16x8*)(k_ws  + base + (size_t)r * HDIM + c0);
        *(s16x8*)&Vts[0][r][cx0] = *(const s16x8*)(vt_ws + base + (size_t)r * S_LEN + c0);
    }
    __syncthreads();

    const short* kp = k_ws  + base + (size_t)(64 + r0) * HDIM + c0;
    const short* vp = vt_ws + base + (size_t)r0 * S_LEN + 64 + c0;

    for (int kt = 0; kt < ntkB; ++kt) {
        const int cur = kt & 1;
        const bool pre = (kt + 1 < ntkB);
        s16x8 ka[4], va[4];
        if (pre) {
            #pragma unroll
            for (int j = 0; j < 4; ++j) {
                ka[j] = *(const s16x8*)(kp + (size_t)j * 16 * HDIM);
                va[j] = *(const s16x8*)(vp + (size_t)j * 16 * S_LEN);
            }
            kp += (size_t)64 * HDIM; vp += 64;
        }

        // ---- LDS fragment reads (shared by both q-tiles) ----
        s16x8 kfa[4][2];
        #pragma unroll
        for (int f = 0; f < 4; ++f)
            #pragma unroll
            for (int c = 0; c < 2; ++c)
                kfa[f][c] = *(const s16x8*)&Ks[cur][f * 16 + r15][(c * 32 + g * 8) ^ swr];
        V8 vfr[4][2];
        #pragma unroll
        for (int f2 = 0; f2 < 4; ++f2)
            #pragma unroll
            for (int kc = 0; kc < 2; ++kc) {
                vfr[f2][kc].h[0] = *(const s16x4*)&Vts[cur][f2 * 16 + r15][(kc * 32 + g * 4) ^ swr];
                vfr[f2][kc].h[1] = *(const s16x4*)&Vts[cur][f2 * 16 + r15][(kc * 32 + 16 + g * 4) ^ swr];
            }

        // ================= tile B (always active) =================
        {
            const bool dg = (kt == ntkB - 1);
            f32x4 z[4];
            __builtin_amdgcn_s_setprio(1);
            #pragma unroll
            for (int f = 0; f < 4; ++f) {
                f32x4 zz = { 0.f, 0.f, 0.f, 0.f };
                zz = mfma16(kfa[f][0], qfB0, zz);
                zz = mfma16(kfa[f][1], qfB1, zz);
                z[f] = zz;
            }
            __builtin_amdgcn_s_setprio(0);
            if (dg) {
                #pragma unroll
                for (int f = 0; f < 4; ++f)
                    #pragma unroll
                    for (int reg = 0; reg < 4; ++reg)
                        if (f * 16 + g * 4 + reg > qrelB) z[f][reg] = -3e30f;
            }
            P8 p8[2];
            #pragma unroll
            for (int f = 0; f < 4; ++f) {
                float e0 = fexp2(z[f][0]);
                float e1 = fexp2(z[f][1]);
                float e2 = fexp2(z[f][2]);
                float e3 = fexp2(z[f][3]);
                lrB += (e0 + e1) + (e2 + e3);
                p8[f >> 1].u[(f & 1) * 2]     = bfpack(e0, e1);
                p8[f >> 1].u[(f & 1) * 2 + 1] = bfpack(e2, e3);
            }
            __builtin_amdgcn_s_setprio(1);
            #pragma unroll
            for (int f2 = 0; f2 < 4; ++f2) {
                oB[f2] = mfma16(vfr[f2][0].v, p8[0].v, oB[f2]);
                oB[f2] = mfma16(vfr[f2][1].v, p8[1].v, oB[f2]);
            }
            __builtin_amdgcn_s_setprio(0);
        }

        // ================= tile A (active while kt < ntkA) =================
        if (kt < ntkA) {
            const bool dg = (kt == ntkA - 1);
            f32x4 z[4];
            __builtin_amdgcn_s_setprio(1);
            #pragma unroll
            for (int f = 0; f < 4; ++f) {
                f32x4 zz = { 0.f, 0.f, 0.f, 0.f };
                zz = mfma16(kfa[f][0], qfA0, zz);
                zz = mfma16(kfa[f][1], qfA1, zz);
                z[f] = zz;
            }
            __builtin_amdgcn_s_setprio(0);
            if (dg) {
                #pragma unroll
                for (int f = 0; f < 4; ++f)
                    #pragma unroll
                    for (int reg = 0; reg < 4; ++reg)
                        if (f * 16 + g * 4 + reg > qrelA) z[f][reg] = -3e30f;
            }
            P8 p8[2];
            #pragma unroll
            for (int f = 0; f < 4; ++f) {
                float e0 = fexp2(z[f][0]);
                float e1 = fexp2(z[f][1]);
                float e2 = fexp2(z[f][2]);
                float e3 = fexp2(z[f][3]);
                lrA += (e0 + e1) + (e2 + e3);
                p8[f >> 1].u[(f & 1) * 2]     = bfpack(e0, e1);
                p8[f >> 1].u[(f & 1) * 2 + 1] = bfpack(e2, e3);
            }
            __builtin_amdgcn_s_setprio(1);
            #pragma unroll
            for (int f2 = 0; f2 < 4; ++f2) {
                oA[f2] = mfma16(vfr[f2][0].v, p8[0].v, oA[f2]);
                oA[f2] = mfma16(vfr[f2][1].v, p8[1].v, oA[f2]);
            }
            __builtin_amdgcn_s_setprio(0);
        }

        if (pre) {
            #pragma unroll
            for (int j = 0; j < 4; ++j) {
                int r = r0 + j * 16;
                *(s16x8*)&Ks[cur ^ 1][r][cx0]  = ka[j];
                *(s16x8*)&Vts[cur ^ 1][r][cx0] = va[j];
            }
        }
        __syncthreads();
    }

    // ---- epilogue: reduce l, normalize, write both tiles ----
    {
        float l = lrA;
        l += __shfl_xor(l, 16);
        l += __shfl_xor(l, 32);
        float inv = 1.f / (l + 1e-8f);
        size_t obase = ((size_t)b * S_LEN + qgA) * HID + h * HDIM + g * 4;
        #pragma unroll
        for (int f2 = 0; f2 < 4; ++f2) {
            s16x4 ov = { f2bf(oA[f2][0] * inv), f2bf(oA[f2][1] * inv),
                         f2bf(oA[f2][2] * inv), f2bf(oA[f2][3] * inv) };
            *(s16x4*)(attn_ws + obase + f2 * 16) = ov;
        }
    }
    {
        float l = lrB;
        l += __shfl_xor(l, 16);
        l += __shfl_xor(l, 32);
        float inv = 1.f / (l + 1e-8f);
        size_t obase = ((size_t)b * S_LEN + qgB) * HID + h * HDIM + g * 4;
        #pragma unroll
        for (int f2 = 0; f2 < 4; ++f2) {
            s16x4 ov = { f2bf(oB[f2][0] * inv), f2bf(oB[f2][1] * inv),
                         f2bf(oB[f2][2] * inv), f2bf(oB[f2][3] * inv) };
            *(s16x4*)(attn_ws + obase + f2 * 16) = ov;
        }
    }
}

// ---------------------------------------------------------------------------
// Kernel 3: out = attn(bf16) @ wob.T -> fp32 (unchanged).
// ---------------------------------------------------------------------------
__global__ __launch_bounds__(256) void wo_gemm2(
    const short* __restrict__ attn, const short* __restrict__ wob,
    float* __restrict__ out)
{
    __shared__ short As[128][64];
    __shared__ short Bs[128][64];
    const int t = threadIdx.x;
    const int lane = t & 63, w = t >> 6;
    const int g = lane >> 4, r15 = lane & 15;
    const int wm = w >> 1, wn = w & 1;
    const int bid = blockIdx.x;
    const int cx = bid & 7, ii = bid >> 3;
    const int mt = cx * 4 + (ii & 3), nt = ii >> 2;
    const int m0 = mt * 128, n0 = nt * 128;
    const int lrow = lane >> 3;
    const int scol = ((lane & 7) ^ lrow) * 8;
    const int rsw = r15 & 7;

    f32x4 acc[4][4] = {};

    for (int k0 = 0; k0 < 1024; k0 += 64) {
        __syncthreads();
        #pragma unroll
        for (int ch = 0; ch < 4; ++ch) {
            const int row = w * 32 + ch * 8;
            gload16(attn + (size_t)(m0 + row + lrow) * 1024 + k0 + scol, &As[row][0]);
            gload16(wob  + (size_t)(n0 + row + lrow) * 1024 + k0 + scol, &Bs[row][0]);
        }
        __syncthreads();
        #pragma unroll
        for (int kk = 0; kk < 2; ++kk) {
            s16x8 af[4], bfr[4];
            #pragma unroll
            for (int mi = 0; mi < 4; ++mi)
                af[mi] = *(const s16x8*)&As[wm * 64 + mi * 16 + r15][((kk * 4 + g) ^ rsw) * 8];
            #pragma unroll
            for (int ni = 0; ni < 4; ++ni)
                bfr[ni] = *(const s16x8*)&Bs[wn * 64 + ni * 16 + r15][((kk * 4 + g) ^ rsw) * 8];
            #pragma unroll
            for (int mi = 0; mi < 4; ++mi)
                #pragma unroll
                for (int ni = 0; ni < 4; ++ni)
                    acc[mi][ni] = mfma16(af[mi], bfr[ni], acc[mi][ni]);
        }
    }

    #pragma unroll
    for (int mi = 0; mi < 4; ++mi)
    #pragma unroll
    for (int ni = 0; ni < 4; ++ni) {
        #pragma unroll
        for (int reg = 0; reg < 4; ++reg) {
            int m = m0 + wm * 64 + mi * 16 + g * 4 + reg;
            int n = n0 + wn * 64 + ni * 16 + r15;
            out[(size_t)m * 1024 + n] = acc[mi][ni][reg];
        }
    }
}

extern "C" void kernel_launch(void* const* d_in, const int* in_sizes, int n_in,
                              void* d_out, int out_size, void* d_ws, size_t ws_size,
                              hipStream_t stream) {
    const float* x  = (const float*)d_in[0];
    const float* wq = (const float*)d_in[1];
    const float* wk = (const float*)d_in[2];
    const float* wv = (const float*)d_in[3];
    const float* wo = (const float*)d_in[4];
    float* out = (float*)d_out;

    const size_t ELEMS = (size_t)BATCH * S_LEN * HID;   // 4,194,304
    short* q_ws    = (short*)d_ws;
    short* k_ws    = q_ws + ELEMS;
    short* vt_ws   = k_ws + ELEMS;
    short* xb      = vt_ws + ELEMS;        // aliased: xb (k0/k1) then attn (k2/k3)
    short* attn_ws = xb;
    short* wcat    = xb + ELEMS;           // 3,145,728
    short* wob     = wcat + 3145728;       // 1,048,576   total ~42MB

    convert_kernel<<<dim3(2048), dim3(256), 0, stream>>>(x, wq, wk, wv, wo, xb, wcat, wob);
    qkv_gemm2<<<dim3(768), dim3(256), 0, stream>>>(xb, wcat, q_ws, k_ws, vt_ws);
    attn_kernel8<<<dim3(1024), dim3(128), 0, stream>>>(q_ws, k_ws, vt_ws, attn_ws);
    wo_gemm2<<<dim3(256), dim3(256), 0, stream>>>(attn_ws, wob, out);
}

// Round 14
// 116.246 us; speedup vs baseline: 1.1109x; 1.0372x over previous
//
#include <hip/hip_runtime.h>
#include <hip/hip_bf16.h>

#define S_LEN 2048
#define NHEAD 16
#define HDIM 64
#define HID 1024
#define BATCH 2
#define TSTR 136   // T-buffer stride (shorts)

typedef __attribute__((ext_vector_type(8))) short s16x8;
typedef __attribute__((ext_vector_type(4))) short s16x4;
typedef __attribute__((ext_vector_type(4))) float f32x4;

__device__ __forceinline__ short f2bf(float f) {
    union { __hip_bfloat16 b; short s; } u;
    u.b = __float2bfloat16(f);
    return u.s;
}
__device__ __forceinline__ float fexp2(float x) {
    return __builtin_amdgcn_exp2f(x);
}
__device__ __forceinline__ f32x4 mfma16(s16x8 a, s16x8 b, f32x4 c) {
    return __builtin_amdgcn_mfma_f32_16x16x32_bf16(a, b, c, 0, 0, 0);
}
__device__ __forceinline__ void gload16(const short* g, short* l) {
    __builtin_amdgcn_global_load_lds(
        (const __attribute__((address_space(1))) void*)g,
        (__attribute__((address_space(3))) void*)l, 16, 0, 0);
}
// pack two f32 -> one u32 of 2 bf16 (round-half-up, inputs finite >=0)
__device__ __forceinline__ unsigned bfpack(float a, float b) {
    unsigned ua = __builtin_bit_cast(unsigned, a) + 0x8000u;
    unsigned ub = __builtin_bit_cast(unsigned, b) + 0x8000u;
    return (ub & 0xFFFF0000u) | (ua >> 16);
}

// ---------------------------------------------------------------------------
// Kernel 0: one-shot fp32 -> bf16 conversion of x and all weights.
// ---------------------------------------------------------------------------
__global__ __launch_bounds__(256) void convert_kernel(
    const float* __restrict__ x,  const float* __restrict__ wq,
    const float* __restrict__ wk, const float* __restrict__ wv,
    const float* __restrict__ wo,
    short* __restrict__ xb, short* __restrict__ wcat, short* __restrict__ wob)
{
    const int F4X = 1048576, F4W = 262144;
    const int total = F4X + 4 * F4W;
    for (int i = blockIdx.x * blockDim.x + threadIdx.x; i < total;
         i += gridDim.x * blockDim.x) {
        const float4* s; short* d; int off;
        if (i < F4X)              { s = (const float4*)x;  d = xb;             off = i; }
        else if (i < F4X + F4W)   { s = (const float4*)wq; d = wcat;           off = i - F4X; }
        else if (i < F4X + 2*F4W) { s = (const float4*)wk; d = wcat + 1048576; off = i - (F4X + F4W); }
        else if (i < F4X + 3*F4W) { s = (const float4*)wv; d = wcat + 2097152; off = i - (F4X + 2*F4W); }
        else                      { s = (const float4*)wo; d = wob;            off = i - (F4X + 3*F4W); }
        float4 v = s[off];
        s16x4 o4 = { f2bf(v.x), f2bf(v.y), f2bf(v.z), f2bf(v.w) };
        *(s16x4*)(d + (size_t)off * 4) = o4;
    }
}

// ---------------------------------------------------------------------------
// Kernel 1: fused QKV GEMM (unchanged: Q pre-scaled 0.125, K by log2e).
// ---------------------------------------------------------------------------
__global__ __launch_bounds__(256) void qkv_gemm2(
    const short* __restrict__ xb, const short* __restrict__ wcat,
    short* __restrict__ q_ws, short* __restrict__ k_ws, short* __restrict__ vt_ws)
{
    __shared__ union SM {
        struct { short A[128][64]; short B[128][64]; } s;
        short T[128][TSTR];
    } sm;
    const int t = threadIdx.x;
    const int lane = t & 63, w = t >> 6;
    const int g = lane >> 4, r15 = lane & 15;
    const int wm = w >> 1, wn = w & 1;
    const int bid = blockIdx.x;
    const int cx = bid & 7, ii = bid >> 3;
    const int mt = cx * 4 + (ii & 3), nt = ii >> 2;
    const int m0 = mt * 128, n0 = nt * 128;
    const int sel = n0 >> 10;
    const int nr0 = n0 & 1023;
    const short* Ag = (sel == 2) ? (wcat + (size_t)(2048 + nr0) * 1024)
                                 : (xb   + (size_t)m0 * 1024);
    const short* Bg = (sel == 2) ? (xb   + (size_t)m0 * 1024)
                                 : (wcat + (size_t)(sel * 1024 + nr0) * 1024);
    const int lrow = lane >> 3;
    const int scol = ((lane & 7) ^ lrow) * 8;
    const int rsw = r15 & 7;
    const float osc = (sel == 0) ? 0.125f : ((sel == 1) ? 1.44269504f : 1.0f);

    f32x4 acc[4][4] = {};

    for (int k0 = 0; k0 < 1024; k0 += 64) {
        __syncthreads();
        #pragma unroll
        for (int ch = 0; ch < 4; ++ch) {
            const int row = w * 32 + ch * 8;
            gload16(Ag + (size_t)(row + lrow) * 1024 + k0 + scol, &sm.s.A[row][0]);
            gload16(Bg + (size_t)(row + lrow) * 1024 + k0 + scol, &sm.s.B[row][0]);
        }
        __syncthreads();
        #pragma unroll
        for (int kk = 0; kk < 2; ++kk) {
            s16x8 af[4], bfr[4];
            #pragma unroll
            for (int mi = 0; mi < 4; ++mi)
                af[mi] = *(const s16x8*)&sm.s.A[wm * 64 + mi * 16 + r15][((kk * 4 + g) ^ rsw) * 8];
            #pragma unroll
            for (int ni = 0; ni < 4; ++ni)
                bfr[ni] = *(const s16x8*)&sm.s.B[wn * 64 + ni * 16 + r15][((kk * 4 + g) ^ rsw) * 8];
            #pragma unroll
            for (int mi = 0; mi < 4; ++mi)
                #pragma unroll
                for (int ni = 0; ni < 4; ++ni)
                    acc[mi][ni] = mfma16(af[mi], bfr[ni], acc[mi][ni]);
        }
    }

    __syncthreads();
    #pragma unroll
    for (int mi = 0; mi < 4; ++mi)
    #pragma unroll
    for (int ni = 0; ni < 4; ++ni)
        #pragma unroll
        for (int reg = 0; reg < 4; ++reg)
            sm.T[wm * 64 + mi * 16 + g * 4 + reg][wn * 64 + ni * 16 + r15]
                = f2bf(acc[mi][ni][reg] * osc);
    __syncthreads();

    const int b = m0 >> 11;
    const int ms = m0 & 2047;
    #pragma unroll
    for (int it = 0; it < 8; ++it) {
        int u = w + it * 4;
        int half = u & 1;
        int rg = u >> 1;
        int r = rg * 8 + lrow;
        int colc = half * 64 + (lane & 7) * 8;
        s16x8 v = *(const s16x8*)&sm.T[r][colc];
        if (sel == 2) {
            int n = nr0 + r;
            int h = n >> 6, d = n & 63;
            *(s16x8*)(vt_ws + ((size_t)(b * NHEAD + h) * HDIM + d) * S_LEN + ms + colc) = v;
        } else {
            int s = ms + r;
            int n = nr0 + colc;
            int h = n >> 6, d = n & 63;
            short* dst = (sel == 0) ? q_ws : k_ws;
            *(s16x8*)(dst + ((size_t)(b * NHEAD + h) * S_LEN + s) * HDIM + d) = v;
        }
    }
}

// ---------------------------------------------------------------------------
// Kernel 2: causal flash attention, Mq=32 per wave + uniform sequential pairs.
// 512 blocks x 128 thr (2 waves).  Block = pair (pi, 31-pi) of 64-row q-tiles
// processed sequentially: ntk sum = 33 for EVERY block.  Each wave owns 32
// q-rows as two 16-row m-subtiles; K/V LDS fragments are read ONCE per tile
// and reused for both m -> LDS bytes/CU halve vs R11.  Staging, swizzles,
// softmax (max-free), PV (K=32 consistent permutation) verbatim from R10/R11.
// ---------------------------------------------------------------------------
__global__ __launch_bounds__(128) void attn_kernel9(
    const short* __restrict__ q_ws, const short* __restrict__ k_ws,
    const short* __restrict__ vt_ws, short* __restrict__ attn_ws)
{
    __shared__ short Ks[2][64][64];
    __shared__ short Vts[2][64][64];
    const int t = threadIdx.x;
    const int lane = t & 63, w = t >> 6;          // w = 0,1
    const int g = lane >> 4, r15 = lane & 15;
    const int bid = blockIdx.x;
    const int lb = (bid & 7) * 64 + (bid >> 3);   // XCD-chunked, 512%8==0
    const int pi = lb & 15;                       // pair index 0..15
    const int bh = lb >> 4;                       // 0..31
    const size_t base = (size_t)bh * S_LEN * HDIM;
    const int swr = (r15 & 7) << 3;
    const int b = bh >> 4, h = bh & 15;

    // staging geometry: 128 threads cover 16 rows x 8 chunks per pass; 4 passes
    const int r0 = t >> 3, c0 = (t & 7) * 8;      // r0 0..15
    const int cx0 = c0 ^ ((r0 & 7) << 3);

    union P8 { unsigned u[4]; s16x8 v; };
    union V8 { s16x4 h[2]; s16x8 v; };

    for (int phase = 0; phase < 2; ++phase) {
        const int qt = phase ? (31 - pi) : pi;    // 64-row tile index 0..31
        const int q0 = qt * 64;
        const int ntk = qt + 1;

        // Q fragments: rows q0 + w*32 + m*16 + r15
        s16x8 qf[2][2];
        #pragma unroll
        for (int m = 0; m < 2; ++m)
            #pragma unroll
            for (int c = 0; c < 2; ++c)
                qf[m][c] = *(const s16x8*)(q_ws + base +
                    (size_t)(q0 + w * 32 + m * 16 + r15) * HDIM + c * 32 + g * 8);
        f32x4 o[2][4] = {};
        float lr[2] = { 0.f, 0.f };

        // prologue: stage KV tile 0 into buffer 0 (4 passes of 16 rows)
        #pragma unroll
        for (int j = 0; j < 4; ++j) {
            int r = r0 + j * 16;
            *(s16x8*)&Ks[0][r][cx0]  = *(const s16x8*)(k_ws  + base + (size_t)r * HDIM + c0);
            *(s16x8*)&Vts[0][r][cx0] = *(const s16x8*)(vt_ws + base + (size_t)r * S_LEN + c0);
        }
        __syncthreads();

        const short* kp = k_ws  + base + (size_t)(64 + r0) * HDIM + c0;
        const short* vp = vt_ws + base + (size_t)r0 * S_LEN + 64 + c0;

        for (int kt = 0; kt < ntk; ++kt) {
            const int cur = kt & 1;
            const bool pre = (kt + 1 < ntk);
            const bool dg = (kt == ntk - 1);
            s16x8 ka[4], va[4];
            if (pre) {
                #pragma unroll
                for (int j = 0; j < 4; ++j) {
                    ka[j] = *(const s16x8*)(kp + (size_t)j * 16 * HDIM);
                    va[j] = *(const s16x8*)(vp + (size_t)j * 16 * S_LEN);
                }
                kp += (size_t)64 * HDIM; vp += 64;
            }

            // ---- LDS fragment reads (ONCE, shared across both m) ----
            s16x8 kfa[4][2];
            #pragma unroll
            for (int f = 0; f < 4; ++f)
                #pragma unroll
                for (int c = 0; c < 2; ++c)
                    kfa[f][c] = *(const s16x8*)&Ks[cur][f * 16 + r15][(c * 32 + g * 8) ^ swr];
            V8 vfr[4][2];
            #pragma unroll
            for (int f2 = 0; f2 < 4; ++f2)
                #pragma unroll
                for (int kc = 0; kc < 2; ++kc) {
                    vfr[f2][kc].h[0] = *(const s16x4*)&Vts[cur][f2 * 16 + r15][(kc * 32 + g * 4) ^ swr];
                    vfr[f2][kc].h[1] = *(const s16x4*)&Vts[cur][f2 * 16 + r15][(kc * 32 + 16 + g * 4) ^ swr];
                }

            #pragma unroll
            for (int m = 0; m < 2; ++m) {
                // ---- QK^T (z = score * 0.125 * log2e via folded weights) ----
                f32x4 z[4];
                __builtin_amdgcn_s_setprio(1);
                #pragma unroll
                for (int f = 0; f < 4; ++f) {
                    f32x4 zz = { 0.f, 0.f, 0.f, 0.f };
                    zz = mfma16(kfa[f][0], qf[m][0], zz);
                    zz = mfma16(kfa[f][1], qf[m][1], zz);
                    z[f] = zz;
                }
                __builtin_amdgcn_s_setprio(0);

                // ---- causal mask (diagonal tile only): exp2(-3e30) = 0 ----
                if (dg) {
                    const int qrel = w * 32 + m * 16 + r15;   // kv0 == q0
                    #pragma unroll
                    for (int f = 0; f < 4; ++f)
                        #pragma unroll
                        for (int reg = 0; reg < 4; ++reg)
                            if (f * 16 + g * 4 + reg > qrel) z[f][reg] = -3e30f;
                }

                // ---- direct exp2 + pack + per-lane sum (max-free) ----
                P8 p8[2];
                #pragma unroll
                for (int f = 0; f < 4; ++f) {
                    float e0 = fexp2(z[f][0]);
                    float e1 = fexp2(z[f][1]);
                    float e2 = fexp2(z[f][2]);
                    float e3 = fexp2(z[f][3]);
                    lr[m] += (e0 + e1) + (e2 + e3);
                    p8[f >> 1].u[(f & 1) * 2]     = bfpack(e0, e1);
                    p8[f >> 1].u[(f & 1) * 2 + 1] = bfpack(e2, e3);
                }

                // ---- PV at K=32, consistent k-permutation ----
                __builtin_amdgcn_s_setprio(1);
                #pragma unroll
                for (int f2 = 0; f2 < 4; ++f2) {
                    o[m][f2] = mfma16(vfr[f2][0].v, p8[0].v, o[m][f2]);
                    o[m][f2] = mfma16(vfr[f2][1].v, p8[1].v, o[m][f2]);
                }
                __builtin_amdgcn_s_setprio(0);
            }

            if (pre) {
                #pragma unroll
                for (int j = 0; j < 4; ++j) {
                    int r = r0 + j * 16;
                    *(s16x8*)&Ks[cur ^ 1][r][cx0]  = ka[j];
                    *(s16x8*)&Vts[cur ^ 1][r][cx0] = va[j];
                }
            }
            __syncthreads();
        }

        // ---- epilogue: reduce l, normalize, write both m-subtiles ----
        #pragma unroll
        for (int m = 0; m < 2; ++m) {
            float l = lr[m];
            l += __shfl_xor(l, 16);
            l += __shfl_xor(l, 32);
            float inv = 1.f / (l + 1e-8f);
            const int qg = q0 + w * 32 + m * 16 + r15;
            size_t obase = ((size_t)b * S_LEN + qg) * HID + h * HDIM + g * 4;
            #pragma unroll
            for (int f2 = 0; f2 < 4; ++f2) {
                s16x4 ov = { f2bf(o[m][f2][0] * inv), f2bf(o[m][f2][1] * inv),
                             f2bf(o[m][f2][2] * inv), f2bf(o[m][f2][3] * inv) };
                *(s16x4*)(attn_ws + obase + f2 * 16) = ov;
            }
        }
        __syncthreads();   // phase boundary: all reads done before restaging
    }
}

// ---------------------------------------------------------------------------
// Kernel 3: out = attn(bf16) @ wob.T -> fp32 (unchanged).
// ---------------------------------------------------------------------------
__global__ __launch_bounds__(256) void wo_gemm2(
    const short* __restrict__ attn, const short* __restrict__ wob,
    float* __restrict__ out)
{
    __shared__ short As[128][64];
    __shared__ short Bs[128][64];
    const int t = threadIdx.x;
    const int lane = t & 63, w = t >> 6;
    const int g = lane >> 4, r15 = lane & 15;
    const int wm = w >> 1, wn = w & 1;
    const int bid = blockIdx.x;
    const int cx = bid & 7, ii = bid >> 3;
    const int mt = cx * 4 + (ii & 3), nt = ii >> 2;
    const int m0 = mt * 128, n0 = nt * 128;
    const int lrow = lane >> 3;
    const int scol = ((lane & 7) ^ lrow) * 8;
    const int rsw = r15 & 7;

    f32x4 acc[4][4] = {};

    for (int k0 = 0; k0 < 1024; k0 += 64) {
        __syncthreads();
        #pragma unroll
        for (int ch = 0; ch < 4; ++ch) {
            const int row = w * 32 + ch * 8;
            gload16(attn + (size_t)(m0 + row + lrow) * 1024 + k0 + scol, &As[row][0]);
            gload16(wob  + (size_t)(n0 + row + lrow) * 1024 + k0 + scol, &Bs[row][0]);
        }
        __syncthreads();
        #pragma unroll
        for (int kk = 0; kk < 2; ++kk) {
            s16x8 af[4], bfr[4];
            #pragma unroll
            for (int mi = 0; mi < 4; ++mi)
                af[mi] = *(const s16x8*)&As[wm * 64 + mi * 16 + r15][((kk * 4 + g) ^ rsw) * 8];
            #pragma unroll
            for (int ni = 0; ni < 4; ++ni)
                bfr[ni] = *(const s16x8*)&Bs[wn * 64 + ni * 16 + r15][((kk * 4 + g) ^ rsw) * 8];
            #pragma unroll
            for (int mi = 0; mi < 4; ++mi)
                #pragma unroll
                for (int ni = 0; ni < 4; ++ni)
                    acc[mi][ni] = mfma16(af[mi], bfr[ni], acc[mi][ni]);
        }
    }

    #pragma unroll
    for (int mi = 0; mi < 4; ++mi)
    #pragma unroll
    for (int ni = 0; ni < 4; ++ni) {
        #pragma unroll
        for (int reg = 0; reg < 4; ++reg) {
            int m = m0 + wm * 64 + mi * 16 + g * 4 + reg;
            int n = n0 + wn * 64 + ni * 16 + r15;
            out[(size_t)m * 1024 + n] = acc[mi][ni][reg];
        }
    }
}

extern "C" void kernel_launch(void* const* d_in, const int* in_sizes, int n_in,
                              void* d_out, int out_size, void* d_ws, size_t ws_size,
                              hipStream_t stream) {
    const float* x  = (const float*)d_in[0];
    const float* wq = (const float*)d_in[1];
    const float* wk = (const float*)d_in[2];
    const float* wv = (const float*)d_in[3];
    const float* wo = (const float*)d_in[4];
    float* out = (float*)d_out;

    const size_t ELEMS = (size_t)BATCH * S_LEN * HID;   // 4,194,304
    short* q_ws    = (short*)d_ws;
    short* k_ws    = q_ws + ELEMS;
    short* vt_ws   = k_ws + ELEMS;
    short* xb      = vt_ws + ELEMS;        // aliased: xb (k0/k1) then attn (k2/k3)
    short* attn_ws = xb;
    short* wcat    = xb + ELEMS;           // 3,145,728
    short* wob     = wcat + 3145728;       // 1,048,576   total ~42MB

    convert_kernel<<<dim3(2048), dim3(256), 0, stream>>>(x, wq, wk, wv, wo, xb, wcat, wob);
    qkv_gemm2<<<dim3(768), dim3(256), 0, stream>>>(xb, wcat, q_ws, k_ws, vt_ws);
    attn_kernel9<<<dim3(512), dim3(128), 0, stream>>>(q_ws, k_ws, vt_ws, attn_ws);
    wo_gemm2<<<dim3(256), dim3(256), 0, stream>>>(attn_ws, wob, out);
}